// Round 1
// baseline (5500.263 us; speedup 1.0000x reference)
//
#include <hip/hip_runtime.h>
#include <cstddef>

// ---------------------------------------------------------------------------
// Mamba forward, fp32 baseline.
// T = B*L = 4096 tokens. D_MODEL=1024, D_INNER=2048, DT_RANK=64, N_STATE=16,
// V2=32002.
// Workspace layout (floats):
//   xz   [4096 x 4096]   16,777,216
//   xc   [4096 x 2048]    8,388,608
//   dbl  [4096 x 96]        393,216
//   dt   [4096 x 2048]    8,388,608
//   y    [4096 x 2048]    8,388,608
//   mo   [4096 x 1024]    4,194,304
// total 46,530,560 floats = 186.1 MB
// ---------------------------------------------------------------------------

__device__ __forceinline__ float sigmoidf_(float x) {
  return 1.0f / (1.0f + __expf(-x));
}

// ---------------- GEMM: xz = emb[x] @ W_in   M=4096 K=1024 N=4096 ----------
__global__ __launch_bounds__(256) void gemm_xz_kernel(
    const int* __restrict__ x, const float* __restrict__ emb,
    const float* __restrict__ W, float* __restrict__ out) {
  __shared__ float As[16][68];  // [k][m], stride 68: 16B aligned, bank-shifted
  __shared__ float Bs[16][68];  // [k][n]
  const int tid = threadIdx.x;
  const int tx = tid & 15, ty = tid >> 4;
  const int m0 = blockIdx.y * 64, n0 = blockIdx.x * 64;
  const int am = tid >> 2, ak = (tid & 3) * 4;
  const int bk = tid >> 4, bn = (tid & 15) * 4;
  const int row = x[m0 + am];
  const float* aptr = emb + (size_t)row * 1024 + ak;
  const float* bptr = W + (size_t)bk * 4096 + n0 + bn;
  float acc[4][4] = {};
  float4 av = *(const float4*)(aptr);
  float4 bv = *(const float4*)(bptr);
  for (int k0 = 0; k0 < 1024; k0 += 16) {
    __syncthreads();
    As[ak + 0][am] = av.x; As[ak + 1][am] = av.y;
    As[ak + 2][am] = av.z; As[ak + 3][am] = av.w;
    *(float4*)&Bs[bk][bn] = bv;
    __syncthreads();
    if (k0 + 16 < 1024) {
      av = *(const float4*)(aptr + k0 + 16);
      bv = *(const float4*)(bptr + (size_t)(k0 + 16) * 4096);
    }
#pragma unroll
    for (int kk = 0; kk < 16; ++kk) {
      float4 a = *(const float4*)&As[kk][ty * 4];
      float4 b = *(const float4*)&Bs[kk][tx * 4];
      float aa[4] = {a.x, a.y, a.z, a.w};
      float bb[4] = {b.x, b.y, b.z, b.w};
#pragma unroll
      for (int i = 0; i < 4; ++i)
#pragma unroll
        for (int j = 0; j < 4; ++j)
          acc[i][j] = fmaf(aa[i], bb[j], acc[i][j]);
    }
  }
#pragma unroll
  for (int i = 0; i < 4; ++i) {
    float4 v = make_float4(acc[i][0], acc[i][1], acc[i][2], acc[i][3]);
    *(float4*)(out + (size_t)(m0 + ty * 4 + i) * 4096 + n0 + tx * 4) = v;
  }
}

// ---------------- depthwise causal conv (taps=4) + SiLU --------------------
__global__ __launch_bounds__(256) void conv_silu_kernel(
    const float* __restrict__ xz, const float* __restrict__ conv_w,
    const float* __restrict__ conv_b, float* __restrict__ xc) {
  const int idx = blockIdx.x * 256 + threadIdx.x;  // t*2048 + d
  const int t = idx >> 11, d = idx & 2047;
  const int l = t & 2047;  // position within batch
  const float4 w = *(const float4*)(conv_w + (size_t)d * 4);
  const float ww[4] = {w.x, w.y, w.z, w.w};
  float s = conv_b[d];
  const float* xm = xz + d;  // xm[t,d] = xz[t*4096 + d]
#pragma unroll
  for (int j = 0; j < 4; ++j) {
    int lj = l - 3 + j;
    if (lj >= 0) s = fmaf(ww[j], xm[(size_t)(t - 3 + j) * 4096], s);
  }
  xc[idx] = s * sigmoidf_(s);
}

// ---------------- dbl = xc @ W_x   M=4096 K=2048 N=96 ----------------------
__global__ __launch_bounds__(256) void gemm_dbl_kernel(
    const float* __restrict__ xc, const float* __restrict__ Wx,
    float* __restrict__ dbl) {
  const int idx = blockIdx.x * 256 + threadIdx.x;  // < (4096/4)*96 = 98304
  const int tq = idx / 96, c = idx % 96;
  const size_t t0 = (size_t)tq * 4;
  const float* a0 = xc + t0 * 2048;
  float acc[4] = {0.f, 0.f, 0.f, 0.f};
  for (int k = 0; k < 2048; k += 4) {
    float w0 = Wx[(size_t)(k + 0) * 96 + c];
    float w1 = Wx[(size_t)(k + 1) * 96 + c];
    float w2 = Wx[(size_t)(k + 2) * 96 + c];
    float w3 = Wx[(size_t)(k + 3) * 96 + c];
#pragma unroll
    for (int i = 0; i < 4; ++i) {
      float4 avv = *(const float4*)(a0 + (size_t)i * 2048 + k);
      acc[i] = fmaf(avv.x, w0, acc[i]);
      acc[i] = fmaf(avv.y, w1, acc[i]);
      acc[i] = fmaf(avv.z, w2, acc[i]);
      acc[i] = fmaf(avv.w, w3, acc[i]);
    }
  }
#pragma unroll
  for (int i = 0; i < 4; ++i) dbl[(t0 + i) * 96 + c] = acc[i];
}

// ---------------- dt = softplus(dt_r @ W_dt + b_dt)  K=64 N=2048 -----------
__global__ __launch_bounds__(256) void gemm_dt_kernel(
    const float* __restrict__ dbl, const float* __restrict__ Wdt,
    const float* __restrict__ b_dt, float* __restrict__ dt) {
  __shared__ float s[4][64];
  const int t0 = (blockIdx.x >> 3) * 4;
  const int d = ((blockIdx.x & 7) << 8) + threadIdx.x;
  {
    int tt = threadIdx.x >> 6, k = threadIdx.x & 63;
    s[tt][k] = dbl[(size_t)(t0 + tt) * 96 + k];
  }
  __syncthreads();
  const float bd = b_dt[d];
  float acc[4] = {bd, bd, bd, bd};
#pragma unroll 16
  for (int k = 0; k < 64; ++k) {
    float w = Wdt[(size_t)k * 2048 + d];
#pragma unroll
    for (int i = 0; i < 4; ++i) acc[i] = fmaf(s[i][k], w, acc[i]);
  }
#pragma unroll
  for (int i = 0; i < 4; ++i) {
    float v = acc[i];
    float sp = (v > 20.f) ? v : log1pf(__expf(v));
    dt[(size_t)(t0 + i) * 2048 + d] = sp;
  }
}

// ---------------- selective scan -------------------------------------------
// thread = (b, d, n): lane = n + 16*(d&3); 16-lane shfl_xor reduce for y.
__global__ __launch_bounds__(256) void scan_kernel(
    const float* __restrict__ dt, const float* __restrict__ xc,
    const float* __restrict__ dbl, const float* __restrict__ A_log,
    float* __restrict__ y) {
  const int tid = threadIdx.x;
  const int n = tid & 15;
  const int dloc = tid >> 4;           // 0..15
  const int b = blockIdx.x >> 7;       // 128 blocks per batch
  const int d = ((blockIdx.x & 127) << 4) + dloc;
  const float A = -__expf(A_log[(size_t)d * 16 + n]);
  float h = 0.f;
  const size_t tb = (size_t)b * 2048;
  const float* dtp = dt + tb * 2048 + d;
  const float* xcp = xc + tb * 2048 + d;
  const float* Bp = dbl + tb * 96 + 64 + n;
  const float* Cp = dbl + tb * 96 + 80 + n;
  float* yo = y + tb * 2048 + d;

  constexpr int CH = 8;  // prefetch depth: hides ~200cyc L2 latency
  float cdt[CH], cx[CH], cB[CH], cC[CH];
#pragma unroll
  for (int j = 0; j < CH; ++j) {
    cdt[j] = dtp[(size_t)j * 2048];
    cx[j] = xcp[(size_t)j * 2048];
    cB[j] = Bp[(size_t)j * 96];
    cC[j] = Cp[(size_t)j * 96];
  }
  for (int t0 = 0; t0 < 2048; t0 += CH) {
    float ndt[CH], nx[CH], nB[CH], nC[CH];
    const bool more = (t0 + CH < 2048);
    if (more) {
#pragma unroll
      for (int j = 0; j < CH; ++j) {
        size_t o = (size_t)(t0 + CH + j);
        ndt[j] = dtp[o * 2048];
        nx[j] = xcp[o * 2048];
        nB[j] = Bp[o * 96];
        nC[j] = Cp[o * 96];
      }
    }
#pragma unroll
    for (int j = 0; j < CH; ++j) {
      float dA = __expf(cdt[j] * A);
      h = fmaf(dA, h, cdt[j] * cx[j] * cB[j]);
      float p = h * cC[j];
      p += __shfl_xor(p, 1);
      p += __shfl_xor(p, 2);
      p += __shfl_xor(p, 4);
      p += __shfl_xor(p, 8);
      if (n == 0) yo[(size_t)(t0 + j) * 2048] = p;
    }
    if (more) {
#pragma unroll
      for (int j = 0; j < CH; ++j) {
        cdt[j] = ndt[j]; cx[j] = nx[j]; cB[j] = nB[j]; cC[j] = nC[j];
      }
    }
  }
}

// ---------------- y = (y + xc*D) * silu(z), in place -----------------------
__global__ __launch_bounds__(256) void ypost_kernel(
    float* __restrict__ y, const float* __restrict__ xc,
    const float* __restrict__ xz, const float* __restrict__ Dskip) {
  const size_t idx = ((size_t)blockIdx.x * 256 + threadIdx.x) * 4;
  const size_t t = idx >> 11;
  const int d = (int)(idx & 2047);
  float4 yv = *(float4*)(y + idx);
  float4 xv = *(const float4*)(xc + idx);
  float4 zv = *(const float4*)(xz + t * 4096 + 2048 + d);
  float4 Dv = *(const float4*)(Dskip + d);
  float yy[4] = {yv.x, yv.y, yv.z, yv.w};
  float xx[4] = {xv.x, xv.y, xv.z, xv.w};
  float zz[4] = {zv.x, zv.y, zv.z, zv.w};
  float dd[4] = {Dv.x, Dv.y, Dv.z, Dv.w};
  float r[4];
#pragma unroll
  for (int i = 0; i < 4; ++i) {
    float t1 = fmaf(xx[i], dd[i], yy[i]);
    r[i] = t1 * (zz[i] * sigmoidf_(zz[i]));
  }
  *(float4*)(y + idx) = make_float4(r[0], r[1], r[2], r[3]);
}

// ---------------- GEMM: mo = y @ W_out   M=4096 K=2048 N=1024 --------------
__global__ __launch_bounds__(256) void gemm_mout_kernel(
    const float* __restrict__ Ain, const float* __restrict__ W,
    float* __restrict__ out) {
  __shared__ float As[16][68];
  __shared__ float Bs[16][68];
  const int tid = threadIdx.x;
  const int tx = tid & 15, ty = tid >> 4;
  const int m0 = blockIdx.y * 64, n0 = blockIdx.x * 64;
  const int am = tid >> 2, ak = (tid & 3) * 4;
  const int bk = tid >> 4, bn = (tid & 15) * 4;
  const float* aptr = Ain + (size_t)(m0 + am) * 2048 + ak;
  const float* bptr = W + (size_t)bk * 1024 + n0 + bn;
  float acc[4][4] = {};
  float4 av = *(const float4*)(aptr);
  float4 bv = *(const float4*)(bptr);
  for (int k0 = 0; k0 < 2048; k0 += 16) {
    __syncthreads();
    As[ak + 0][am] = av.x; As[ak + 1][am] = av.y;
    As[ak + 2][am] = av.z; As[ak + 3][am] = av.w;
    *(float4*)&Bs[bk][bn] = bv;
    __syncthreads();
    if (k0 + 16 < 2048) {
      av = *(const float4*)(aptr + k0 + 16);
      bv = *(const float4*)(bptr + (size_t)(k0 + 16) * 1024);
    }
#pragma unroll
    for (int kk = 0; kk < 16; ++kk) {
      float4 a = *(const float4*)&As[kk][ty * 4];
      float4 b = *(const float4*)&Bs[kk][tx * 4];
      float aa[4] = {a.x, a.y, a.z, a.w};
      float bb[4] = {b.x, b.y, b.z, b.w};
#pragma unroll
      for (int i = 0; i < 4; ++i)
#pragma unroll
        for (int j = 0; j < 4; ++j)
          acc[i][j] = fmaf(aa[i], bb[j], acc[i][j]);
    }
  }
#pragma unroll
  for (int i = 0; i < 4; ++i) {
    float4 v = make_float4(acc[i][0], acc[i][1], acc[i][2], acc[i][3]);
    *(float4*)(out + (size_t)(m0 + ty * 4 + i) * 1024 + n0 + tx * 4) = v;
  }
}

// ---------------- GEMM: logits = mo @ W_head + b_head, store transposed ----
// M=4096 K=1024 N=32002; out[b, n, l] = logits[t=b*2048+l, n]
// thread roles swapped vs normal gemm: tx indexes M (=l) so stores coalesce.
__global__ __launch_bounds__(256) void gemm_head_kernel(
    const float* __restrict__ Ain, const float* __restrict__ W,
    const float* __restrict__ bias, float* __restrict__ out) {
  __shared__ float As[16][68];
  __shared__ float Bs[16][68];
  const int tid = threadIdx.x;
  const int tx = tid & 15, ty = tid >> 4;
  const int m0 = blockIdx.y * 64, n0 = blockIdx.x * 64;
  const int am = tid >> 2, ak = (tid & 3) * 4;
  const int bk = tid >> 4, bn = (tid & 15) * 4;
  const float* aptr = Ain + (size_t)(m0 + am) * 1024 + ak;
  const int bcol = n0 + bn;
  const bool btail = (bcol + 3 >= 32002);
  const float* bptr = W + (size_t)bk * 32002 + bcol;
  float acc[4][4] = {};  // [n_sub][m_sub]

  auto load_b = [&](int k0) -> float4 {
    if (!btail) return *(const float4*)(bptr + (size_t)k0 * 32002);
    float e[4];
#pragma unroll
    for (int j = 0; j < 4; ++j)
      e[j] = (bcol + j < 32002) ? bptr[(size_t)k0 * 32002 + j] : 0.f;
    return make_float4(e[0], e[1], e[2], e[3]);
  };

  float4 av = *(const float4*)(aptr);
  float4 bv = load_b(0);
  for (int k0 = 0; k0 < 1024; k0 += 16) {
    __syncthreads();
    As[ak + 0][am] = av.x; As[ak + 1][am] = av.y;
    As[ak + 2][am] = av.z; As[ak + 3][am] = av.w;
    *(float4*)&Bs[bk][bn] = bv;
    __syncthreads();
    if (k0 + 16 < 1024) {
      av = *(const float4*)(aptr + k0 + 16);
      bv = load_b(k0 + 16);
    }
#pragma unroll
    for (int kk = 0; kk < 16; ++kk) {
      float4 a = *(const float4*)&As[kk][tx * 4];  // m fragment
      float4 b = *(const float4*)&Bs[kk][ty * 4];  // n fragment
      float aa[4] = {a.x, a.y, a.z, a.w};
      float bb[4] = {b.x, b.y, b.z, b.w};
#pragma unroll
      for (int j = 0; j < 4; ++j)
#pragma unroll
        for (int i = 0; i < 4; ++i)
          acc[j][i] = fmaf(bb[j], aa[i], acc[j][i]);
    }
  }
  const int b_idx = m0 >> 11;           // batch
  const int l0 = (m0 & 2047) + tx * 4;  // position within batch
#pragma unroll
  for (int j = 0; j < 4; ++j) {
    int nn = n0 + ty * 4 + j;
    if (nn < 32002) {
      float bb = bias[nn];
      float4 v = make_float4(acc[j][0] + bb, acc[j][1] + bb,
                             acc[j][2] + bb, acc[j][3] + bb);
      *(float4*)(out + ((size_t)b_idx * 32002 + nn) * 2048 + l0) = v;
    }
  }
}

// ---------------------------------------------------------------------------
extern "C" void kernel_launch(void* const* d_in, const int* in_sizes, int n_in,
                              void* d_out, int out_size, void* d_ws,
                              size_t ws_size, hipStream_t stream) {
  const int* x = (const int*)d_in[0];
  const float* emb = (const float*)d_in[1];
  const float* W_in = (const float*)d_in[2];
  const float* conv_w = (const float*)d_in[3];
  const float* conv_b = (const float*)d_in[4];
  const float* W_x = (const float*)d_in[5];
  const float* W_dt = (const float*)d_in[6];
  const float* b_dt = (const float*)d_in[7];
  const float* A_log = (const float*)d_in[8];
  const float* D_skip = (const float*)d_in[9];
  const float* W_out = (const float*)d_in[10];
  const float* W_head = (const float*)d_in[11];
  const float* b_head = (const float*)d_in[12];
  float* out = (float*)d_out;

  float* ws = (float*)d_ws;
  float* xz = ws;                   // 16,777,216
  float* xc = xz + 16777216;        //  8,388,608
  float* dbl = xc + 8388608;        //    393,216
  float* dt = dbl + 393216;         //  8,388,608
  float* y = dt + 8388608;          //  8,388,608
  float* mo = y + 8388608;          //  4,194,304

  dim3 blk(256);
  gemm_xz_kernel<<<dim3(64, 64), blk, 0, stream>>>(x, emb, W_in, xz);
  conv_silu_kernel<<<32768, blk, 0, stream>>>(xz, conv_w, conv_b, xc);
  gemm_dbl_kernel<<<384, blk, 0, stream>>>(xc, W_x, dbl);
  gemm_dt_kernel<<<8192, blk, 0, stream>>>(dbl, W_dt, b_dt, dt);
  scan_kernel<<<256, blk, 0, stream>>>(dt, xc, dbl, A_log, y);
  ypost_kernel<<<8192, blk, 0, stream>>>(y, xc, xz, D_skip);
  gemm_mout_kernel<<<dim3(16, 64), blk, 0, stream>>>(y, W_out, mo);
  gemm_head_kernel<<<dim3(501, 64), blk, 0, stream>>>(mo, W_head, b_head, out);
}